// Round 3
// baseline (874.583 us; speedup 1.0000x reference)
//
#include <hip/hip_runtime.h>
#include <hip/hip_bf16.h>
#include <stdint.h>

// Problem: B=64, T=128, F=16, H=512, S=2.  All inputs fp32, lengths int32, out fp32 [64][14].
//
// History: R2 1338us -> R3 relaxed poll 831 -> R5 poll-on-data 656 -> R6 coalesced poll 612
// -> R9 dense transactions (lstmk 400, MALL-RT floor) -> R11 gemmB m97-staging, total 590
// -> R12 fused gemm-under-recurrence 570 -> R13 gemm LDS swizzle (conflicts 2.16e7->6.5e6,
//    time NEUTRAL -> gemm off critical path; recurrence hop is everything).
// Failed: R4 release-flags, R7 poll backoff, R8 64x512, R10 XCD-local sc0 (no consensus,
//    stale-L2 poisoning suspected).
//
// R14: XCD-LOCAL FAST PATH WITH RUNTIME CONSENSUS + lstm setprio:
//   - peers for (g,rr) are exactly (g',rr): all share bid%8==rr -> same XCD under the
//     round-robin mapping (m09). Each lstm block reads HW_REG_XCC_ID, publishes to
//     xcdtab[bid] (agent), polls its 15 peers; fast mode iff all 16 match (symmetric ->
//     group-consistent). Bounded spin -> fallback = R13 agent path (correct regardless).
//   - fast mode: h stores = volatile u64 (write-back, stays in shared L2); h polls =
//     volatile u64 loads (sc0: L1-bypass, L2-hit). Same-L2 coherence updates the polled
//     sentinel line in place -> no stale-line deadlock (R10's suspected failure).
//     Cuts the per-step hop from MALL RT (~1000+cy) to L2 RT (~300cy).
//   - lstm waves s_setprio(2): win issue arbitration vs co-resident gemm waves.
//   - WRITE_SIZE signature: 164MB (8B agent stores -> 64B write-through lines) should
//     drop to ~55MB when fast path engages.
//
// Reshape quirk (faithful to torch): segment s', step t' uses source timestep n_t=(s'*128+t')>>1
// and embedding branch n_s=(s'*128+t')&1.

typedef __attribute__((ext_vector_type(8))) short bf16x8_t;
typedef __attribute__((ext_vector_type(4))) float f32x4_t;

#define SENT 0xAAAAAAAAu

// ---------------- workspace layout (bytes) ----------------
#define OFF_G      0u                      // bf16 [8192][2048] time-major rows  33,554,432
#define OFF_TEMB   33554432u               // bf16 [8192][1024]   16,777,216
#define OFF_HH     50331648u               // bf16 [129][8rr][16cg][16row][32u] 16,908,288
#define OFF_WHH    67239936u               // bf16 [2048][512]     2,097,152
#define OFF_WMID   69337088u               // bf16 [2048][1024]    4,194,304
#define OFF_WC0    73531392u               // f32  [2048][8]          65,536
#define OFF_WC1    73596928u               // f32  [2048][8] (6 used) 65,536
#define OFF_BC     73662464u               // f32  [2][2048]          16,384
#define OFF_HFIN   73678848u               // f32  [64][1024]        262,144
#define OFF_GFLAG  73940992u               // u32  [64][16]             4,096
#define OFF_XCDT   73945088u               // u32  [128]                  512
// total ~74 MB

__device__ __forceinline__ float bf2f(uint16_t u){
  union { uint32_t i; float f; } v; v.i = ((uint32_t)u) << 16; return v.f;
}
__device__ __forceinline__ uint16_t f2b(float f){
  union { float f; uint32_t i; } v; v.f = f;
  uint32_t r = v.i + 0x7fffu + ((v.i >> 16) & 1u);  // RNE
  return (uint16_t)(r >> 16);
}
__device__ __forceinline__ float sigm(float x){ return 1.0f/(1.0f + __expf(-x)); }
__device__ __forceinline__ float tanh_(float x){
  float xc = fminf(fmaxf(x, -15.f), 15.f);
  float t = __expf(2.f*xc);
  return (t - 1.f)/(t + 1.f);
}
__device__ __forceinline__ void gl_lds16(const void* g, void* l){
  __builtin_amdgcn_global_load_lds(
      (const __attribute__((address_space(1))) void*)g,
      (__attribute__((address_space(3))) void*)l, 16, 0, 0);
}

// ---------------- prepAll: prep1(2048) | tembk(8192) | lvl0+gflag(128) | sentinel(2048) ------
__global__ void prepAll(const float* __restrict__ x,
                        const float* __restrict__ W_ih, const float* __restrict__ W_hh,
                        const float* __restrict__ W_is0, const float* __restrict__ b_is0,
                        const float* __restrict__ W_is1, const float* __restrict__ b_is1,
                        const float* __restrict__ b_ih, const float* __restrict__ b_hh,
                        const float* __restrict__ h0,
                        uint16_t* __restrict__ whh_b, uint16_t* __restrict__ wmid_b,
                        float* __restrict__ wc0, float* __restrict__ wc1,
                        float* __restrict__ bc,
                        uint16_t* __restrict__ temb, uint16_t* __restrict__ h_hist,
                        uint32_t* __restrict__ gflag, uint32_t* __restrict__ xcdtab){
  const int bid = blockIdx.x, tid = threadIdx.x;
  if (bid < 2048){
    // ---- prep1 role: weight folding + bf16 casts ----
    const int n = bid;
    __shared__ float wrow[512];
    __shared__ float red[16][17];
    wrow[tid]       = W_ih[(size_t)n*1536 + tid];
    wrow[tid + 256] = W_ih[(size_t)n*1536 + 256 + tid];
    for (int j = tid; j < 1024; j += 256)
      wmid_b[(size_t)n*1024 + j] = f2b(W_ih[(size_t)n*1536 + 512 + j]);
    for (int k = tid; k < 512; k += 256)
      whh_b[(size_t)n*512 + k] = f2b(W_hh[(size_t)n*512 + k]);
    __syncthreads();
    {
      const int d = tid >> 4, jp = tid & 15;
      float s = 0.f;
      const int kk0 = jp*32;
      if (d < 8){
        for (int k = kk0; k < kk0 + 32; ++k) s += wrow[k]*W_is0[k*8 + d];
      } else if (d < 14){
        int c = d - 8;
        for (int k = kk0; k < kk0 + 32; ++k) s += wrow[k]*W_is1[k*6 + c];
      } else if (d == 14){
        for (int k = kk0; k < kk0 + 32; ++k) s += wrow[k]*b_is0[k];
      } else {
        for (int k = kk0; k < kk0 + 32; ++k) s += wrow[k]*b_is1[k];
      }
      red[d][jp] = s;
    }
    __syncthreads();
    if (tid < 16){
      float tot = 0.f;
      #pragma unroll
      for (int i = 0; i < 16; ++i) tot += red[tid][i];
      if (tid < 8)        wc0[n*8 + tid] = tot;
      else if (tid < 14)  wc1[n*8 + (tid - 8)] = tot;
      else if (tid == 14) bc[n]        = b_ih[n] + b_hh[n] + tot;
      else                bc[2048 + n] = b_ih[n] + b_hh[n] + tot;
    } else if (tid == 16){
      wc1[n*8 + 6] = 0.f; wc1[n*8 + 7] = 0.f;
    }
  } else if (bid < 10240){
    // ---- tembk role ----
    const int rid = bid - 2048;       // (b*128 + t)
    const int k = tid;
    float x0 = x[(size_t)rid*16 + 0], x1 = x[(size_t)rid*16 + 1];
    float f = __expf((float)k * (-9.210340371976184f/256.f));
    float a0 = x0*f, a1 = x1*f;
    size_t base = (size_t)rid*1024;
    temb[base + k]        = f2b(__cosf(a0));
    temb[base + 256 + k]  = f2b(__sinf(a0));
    temb[base + 512 + k]  = f2b(__cosf(a1));
    temb[base + 768 + k]  = f2b(__sinf(a1));
  } else if (bid < 10368){
    // ---- level-0 h + gflag zero + xcdtab init ----
    int i = (bid - 10240)*256 + tid;   // 0..32767
    uint32_t* hh = (uint32_t*)h_hist;
    int e    = i*2;
    int rrcg = e >> 9;
    int rr   = rrcg >> 4, cg = rrcg & 15;
    int rm   = e & 511;
    int row  = rm >> 5, u = rm & 31;
    int b    = (rr*16 + row) & 63;
    int unit = cg*32 + u;
    uint32_t lo = f2b(h0[(size_t)b*512 + unit]);
    uint32_t hi = f2b(h0[(size_t)b*512 + unit + 1]);
    uint32_t wd = lo | (hi << 16);
    if (wd == SENT) wd ^= 1u;
    hh[i] = wd;
    if (i < 1024) gflag[i] = 0u;
    if (i < 128)  xcdtab[i] = 0xFFFFFFFFu;
  } else {
    // ---- sentinel fill role: words [32768, 4227072), 8 per thread via 2x uint4 ----
    uint32_t* hh = (uint32_t*)h_hist;
    size_t w0 = 32768u + ((size_t)(bid - 10368)*256 + tid)*8;
    uint4 s4 = make_uint4(SENT, SENT, SENT, SENT);
    *(uint4*)&hh[w0]     = s4;
    *(uint4*)&hh[w0 + 4] = s4;
  }
}

// ---------------- fused: lstm role (bid 0..127) + gemm role (bid 128..1151) ----------------
// lstm: 8 row-groups x 16 col-groups, blockIdx = g*8 + rr (R9-exact protocol).
// h_hist level layout: [rr][cg16][row16][u32], 1KB/region. G time-major: row' = ntm*64 + b.
__launch_bounds__(256)
__global__ void fusedk(const float* __restrict__ x, const float* __restrict__ c0,
                       const int* __restrict__ lengths,
                       const uint16_t* __restrict__ whh_b, const uint16_t* __restrict__ temb,
                       const uint16_t* __restrict__ wmid,
                       const float* __restrict__ wc0, const float* __restrict__ wc1,
                       const float* __restrict__ bc,
                       uint16_t* __restrict__ G, uint16_t* __restrict__ h_hist,
                       uint32_t* __restrict__ gflag, uint32_t* __restrict__ xcdtab,
                       float* __restrict__ hfin){
  __shared__ __align__(16) uint16_t smem_u[17664];   // lstm: h_l[2][16][552]; gemm: tiles+bounce
  const int tid = threadIdx.x;
  const int bid = blockIdx.x;
  const int w = tid >> 6, lane = tid & 63;
  const int q = lane >> 4, ln = lane & 15;

  if (bid >= 128){
    // ================= gemm role =================
    const int gb = bid - 128;
    const int idx = gb >> 4;
    const int mt = (idx & 1) ? (idx >> 1) : (32 + (idx >> 1));  // seg1 tiles first
    const int n0 = (gb & 15)*128;
    uint16_t* Al = smem_u;
    uint16_t* Bl = smem_u + 8192;
    const int wm = w >> 1, wn = w & 1;
    // T2 swizzle: LDS dest stays LINEAR (global_load_lds writes base+lane*16); the
    // per-lane GLOBAL source fetches chunk (l&7)^(l>>3) of its row (row0&7==0 always),
    // so LDS row r holds chunk cc at 16B-slot cc^(r&7). Reads XOR the same involution.
    const int srow_l = lane >> 3;
    const int scol = (((lane & 7) ^ srow_l)) * 8;   // swizzled source col (elements)

    f32x4_t acc[4][4];
    #pragma unroll
    for (int a = 0; a < 4; ++a)
      #pragma unroll
      for (int b2 = 0; b2 < 4; ++b2) acc[a][b2] = (f32x4_t){0.f,0.f,0.f,0.f};

    for (int kb = 0; kb < 16; ++kb){
      #pragma unroll
      for (int i = 0; i < 4; ++i){
        int row0 = w*32 + i*8;
        int lrow = row0 + srow_l;
        int bA = lrow & 63, ntmA = mt*2 + (lrow >> 6);
        gl_lds16(temb + (size_t)(bA*128 + ntmA)*1024 + kb*64 + scol, &Al[row0*64]);
        gl_lds16(wmid + (size_t)(n0 + lrow)*1024 + kb*64 + scol, &Bl[row0*64]);
      }
      __syncthreads();
      #pragma unroll
      for (int kc = 0; kc < 2; ++kc){
        const int sl = ((((kc << 2) | q) ^ (ln & 7)) << 3);  // swizzled 16B slot (elements)
        bf16x8_t af[4], bf[4];
        #pragma unroll
        for (int mt_i = 0; mt_i < 4; ++mt_i)
          af[mt_i] = *(const bf16x8_t*)&Al[(wm*64 + mt_i*16 + ln)*64 + sl];
        #pragma unroll
        for (int nt = 0; nt < 4; ++nt)
          bf[nt] = *(const bf16x8_t*)&Bl[(wn*64 + nt*16 + ln)*64 + sl];
        #pragma unroll
        for (int mt_i = 0; mt_i < 4; ++mt_i)
          #pragma unroll
          for (int nt = 0; nt < 4; ++nt)
            acc[mt_i][nt] = __builtin_amdgcn_mfma_f32_16x16x32_bf16(af[mt_i], bf[nt], acc[mt_i][nt], 0, 0, 0);
      }
      __syncthreads();
    }
    // C bounce (C/D: col=lane&15, row=quad*4+reg — m89-verified). Stride 132 (pad).
    #pragma unroll
    for (int mt_i = 0; mt_i < 4; ++mt_i)
      #pragma unroll
      for (int nt = 0; nt < 4; ++nt)
        #pragma unroll
        for (int r = 0; r < 4; ++r){
          int Mr = wm*64 + mt_i*16 + q*4 + r;
          int Nc = wn*64 + nt*16 + ln;
          smem_u[Mr*132 + Nc] = f2b(acc[mt_i][nt][r]);
        }
    __syncthreads();
    // epilogue: agent-scope (MALL write-through) stores, 128B/thread contiguous
    {
      const int erow = tid >> 1, eh = tid & 1;
      const unsigned long long* lsrc = (const unsigned long long*)&smem_u[erow*132 + eh*64];
      unsigned long long* gdst = (unsigned long long*)
          (G + (size_t)(mt*128 + erow)*2048 + n0 + eh*64);
      #pragma unroll
      for (int i2 = 0; i2 < 16; ++i2)
        __hip_atomic_store(&gdst[i2], lsrc[i2], __ATOMIC_RELAXED, __HIP_MEMORY_SCOPE_AGENT);
    }
    __syncthreads();   // each wave drains vmcnt(0) before barrier -> all stores in MALL
    if (tid == 0)
      __hip_atomic_store(&gflag[mt*16 + (gb & 15)], 1u,
                         __ATOMIC_RELEASE, __HIP_MEMORY_SCOPE_AGENT);
    return;
  }

  // ================= lstm role (R9-exact + XCD-local fast path + setprio) =================
  __builtin_amdgcn_s_setprio(2);   // recurrence wins issue arbitration vs gemm waves
  #define HL(b,r,c) smem_u[(((b)*16 + (r))*552) + (c)]
  const int rr = bid & 7;
  const int g  = bid >> 3;
  const int k0 = g*32;
  const int sp = rr >> 2;
  const int u8 = ln & 7, gh = ln >> 3;
  const int unit = k0 + w*8 + u8;
  const int gl0 = gh*512 + unit;
  const int gl1 = (2 + gh)*512 + unit;
  const int LVL = 65536;

  bf16x8_t barr0[16], barr1[16];
  #pragma unroll
  for (int kc = 0; kc < 16; ++kc){
    barr0[kc] = *(const bf16x8_t*)(whh_b + (size_t)gl0*512 + kc*32 + q*8);
    barr1[kc] = *(const bf16x8_t*)(whh_b + (size_t)gl1*512 + kc*32 + q*8);
  }
  bf16x8_t e0f[2], e1f[2];
  #pragma unroll
  for (int nsI = 0; nsI < 2; ++nsI){
    bf16x8_t v0 = {0,0,0,0,0,0,0,0}, v1 = {0,0,0,0,0,0,0,0};
    if (q == 0){
      const float* wcs = nsI ? wc1 : wc0;
      #pragma unroll
      for (int jj = 0; jj < 8; ++jj){
        ((uint16_t*)&v0)[jj] = f2b(wcs[gl0*8 + jj]);
        ((uint16_t*)&v1)[jj] = f2b(wcs[gl1*8 + jj]);
      }
    }
    e0f[nsI] = v0; e1f[nsI] = v1;
  }
  float bc0v[2] = { bc[gl0], bc[2048 + gl0] };
  float bc1v[2] = { bc[gl1], bc[2048 + gl1] };

  int   bmr[4], lenr[4];
  float cst[4];
  #pragma unroll
  for (int r = 0; r < 4; ++r){
    int row = rr*16 + q*4 + r;
    bmr[r]  = row & 63;
    lenr[r] = lengths[bmr[r]];
    cst[r]  = c0[(size_t)bmr[r]*512 + unit];
  }

  const int prow = lane >> 2;
  const int pcol = (lane & 3)*8;
  const int xm = tid >> 3, xc = tid & 7;
  const int xb = (rr*16 + xm) & 63;
  const size_t stb = ((size_t)rr*8192 + g*512);

  for (int idx2 = tid; idx2 < 2*16*32; idx2 += 256)
    HL(idx2 >> 9, (idx2 >> 5) & 15, 520 + (idx2 & 31)) = 0;

  // --- R14 XCD consensus: fast (same-L2) mode iff all 16 peers (g',rr) share our XCD ---
  int fastv = 0;
  {
    uint32_t myxcd;
    asm volatile("s_getreg_b32 %0, hwreg(HW_REG_XCC_ID)" : "=s"(myxcd));
    if (tid == 0)
      __hip_atomic_store(&xcdtab[bid], myxcd, __ATOMIC_RELAXED, __HIP_MEMORY_SCOPE_AGENT);
    uint32_t pv = 0xFFFFFFFFu;
    if (tid < 16){
      const uint32_t* pp = &xcdtab[tid*8 + rr];
      for (int it = 0; it < 20000; ++it){
        pv = __hip_atomic_load(pp, __ATOMIC_RELAXED, __HIP_MEMORY_SCOPE_AGENT);
        if (pv != 0xFFFFFFFFu) break;
        __builtin_amdgcn_s_sleep(4);
      }
    }
    bool ok = (tid >= 16) || (pv == myxcd);
    if (tid < 64){
      bool allok = __all(ok);
      if (tid == 0) *(volatile int*)&smem_u[0] = allok ? 1 : 0;
    }
    __syncthreads();
    fastv = *(volatile int*)&smem_u[0];
    __syncthreads();
  }

  // gflag prefetch: fl[] holds flags for the NEXT boundary's m-tile, loaded 4 steps
  // early (latency hidden under the h-poll). Spin fallback keeps correctness.
  uint32_t fl[4];
  {
    const uint32_t* gf0 = gflag + (sp*32)*16 + (g >> 2);
    #pragma unroll
    for (int j = 0; j < 4; ++j)
      fl[j] = __hip_atomic_load(&gf0[j*4], __ATOMIC_RELAXED, __HIP_MEMORY_SCOPE_AGENT);
  }

  for (int t = 0; t < 128; ++t){
    const int qidx = sp*128 + t;
    const int ntm = qidx >> 1;
    const int ns  = qidx & 1;
    const int buf = t & 1;

    // --- gate on G m-tile readiness (prefetched; spin only if stale-false) ---
    if ((t & 3) == 0){
      const int mt = qidx >> 2;
      bool ok = (fl[0] != 0u) & (fl[1] != 0u) & (fl[2] != 0u) & (fl[3] != 0u);
      if (!ok){
        const uint32_t* gf = gflag + mt*16 + (g >> 2);
        while (true){
          ok = true;
          #pragma unroll
          for (int j = 0; j < 4; ++j){
            uint32_t v = __hip_atomic_load(&gf[j*4], __ATOMIC_RELAXED, __HIP_MEMORY_SCOPE_AGENT);
            ok &= (v != 0u);
          }
          if (ok) break;
          __builtin_amdgcn_s_sleep(1);
        }
      }
      if (t < 124){
        const uint32_t* gfn = gflag + (mt + 1)*16 + (g >> 2);
        #pragma unroll
        for (int j = 0; j < 4; ++j)
          fl[j] = __hip_atomic_load(&gfn[j*4], __ATOMIC_RELAXED, __HIP_MEMORY_SCOPE_AGENT);
      }
    }

    // --- early independent loads: G slice (time-major rows, cached) + xf source ---
    uint16_t g0r[4], g1r[4];
    #pragma unroll
    for (int r = 0; r < 4; ++r){
      size_t grow = (size_t)(ntm*64 + bmr[r])*2048;
      g0r[r] = G[grow + gl0];
      g1r[r] = G[grow + gl1];
    }
    float xv = 0.f;
    if (tid < 128){
      if (ns == 0)      xv = x[(size_t)(xb*128 + ntm)*16 + 2 + xc];
      else if (xc < 6)  xv = x[(size_t)(xb*128 + ntm)*16 + 10 + xc];
    }

    // --- hot poll-on-data, lane-dense (R9); fast mode = volatile sc0 loads (L2-hit) ---
    {
      const unsigned long long* lvl = (const unsigned long long*)h_hist
                                      + (((size_t)t*LVL + (size_t)rr*8192) >> 2);
      unsigned long long hv[4][2];
      while (true){
        bool ok = true;
        if (fastv){
          #pragma unroll
          for (int i = 0; i < 4; ++i){
            const volatile unsigned long long* p =
                (const volatile unsigned long long*)
                (lvl + ((size_t)(w*4 + i)*128 + prow*8 + (pcol >> 2)));
            hv[i][0] = p[0];
            hv[i][1] = p[1];
            ok &= ((uint32_t)hv[i][0] != SENT) & ((uint32_t)(hv[i][0] >> 32) != SENT)
                & ((uint32_t)hv[i][1] != SENT) & ((uint32_t)(hv[i][1] >> 32) != SENT);
          }
        } else {
          #pragma unroll
          for (int i = 0; i < 4; ++i){
            const unsigned long long* p = lvl + ((size_t)(w*4 + i)*128 + prow*8 + (pcol >> 2));
            hv[i][0] = __hip_atomic_load(&p[0], __ATOMIC_RELAXED, __HIP_MEMORY_SCOPE_AGENT);
            hv[i][1] = __hip_atomic_load(&p[1], __ATOMIC_RELAXED, __HIP_MEMORY_SCOPE_AGENT);
            ok &= ((uint32_t)hv[i][0] != SENT) & ((uint32_t)(hv[i][0] >> 32) != SENT)
                & ((uint32_t)hv[i][1] != SENT) & ((uint32_t)(hv[i][1] >> 32) != SENT);
          }
        }
        if (__all(ok)) break;
        __builtin_amdgcn_s_sleep(1);
      }
      #pragma unroll
      for (int i = 0; i < 4; ++i){
        int reg = w*4 + i;
        *(unsigned long long*)&HL(buf, prow, reg*32 + pcol)     = hv[i][0];
        *(unsigned long long*)&HL(buf, prow, reg*32 + pcol + 4) = hv[i][1];
      }
    }
    if (tid < 128) HL(buf, xm, 512 + xc) = f2b(xv);
    __syncthreads();

    // --- gates = G + bias + [h|xf] @ [Whh|Wc]^T ---
    f32x4_t acc0, acc1;
    {
      float b0 = ns ? bc0v[1] : bc0v[0];
      float b1 = ns ? bc1v[1] : bc1v[0];
      #pragma unroll
      for (int r = 0; r < 4; ++r){ acc0[r] = bf2f(g0r[r]) + b0; acc1[r] = bf2f(g1r[r]) + b1; }
    }
    #pragma unroll
    for (int kc = 0; kc < 16; ++kc){
      bf16x8_t a = *(const bf16x8_t*)&HL(buf, ln, kc*32 + q*8);
      acc0 = __builtin_amdgcn_mfma_f32_16x16x32_bf16(a, barr0[kc], acc0, 0, 0, 0);
      acc1 = __builtin_amdgcn_mfma_f32_16x16x32_bf16(a, barr1[kc], acc1, 0, 0, 0);
    }
    {
      bf16x8_t a = *(const bf16x8_t*)&HL(buf, ln, 512 + q*8);
      acc0 = __builtin_amdgcn_mfma_f32_16x16x32_bf16(a, ns ? e0f[1] : e0f[0], acc0, 0, 0, 0);
      acc1 = __builtin_amdgcn_mfma_f32_16x16x32_bf16(a, ns ? e1f[1] : e1f[0], acc1, 0, 0, 0);
    }

    float pf[4], po[4];
    #pragma unroll
    for (int r = 0; r < 4; ++r){
      pf[r] = __shfl_xor(acc0[r], 8);
      po[r] = __shfl_xor(acc1[r], 8);
    }
    if (ln < 8){
      uint32_t hb[4]; float hF[4];
      #pragma unroll
      for (int r = 0; r < 4; ++r){
        float ig = acc0[r], fg = pf[r], gg = acc1[r], og = po[r];
        cst[r] = sigm(fg)*cst[r] + sigm(ig)*tanh_(gg);
        float h = sigm(og)*tanh_(cst[r]);
        hF[r] = h; hb[r] = (uint32_t)f2b(h);
      }
      #pragma unroll
      for (int r = 0; r < 4; ++r){
        uint32_t ph = (uint32_t)__shfl_xor((int)hb[r], 1);
        uint32_t packed = hb[r] | (ph << 16);
        if (packed == SENT) packed ^= 1u;
        uint32_t hi = (uint32_t)__shfl_xor((int)packed, 2);
        if ((ln & 3) == 0){
          unsigned long long v = (unsigned long long)packed | ((unsigned long long)hi << 32);
          unsigned long long* hp = (unsigned long long*)h_hist
              + (((size_t)(t+1)*LVL + stb + (size_t)(q*4 + r)*32 + w*8 + u8) >> 2);
          if (fastv) *(volatile unsigned long long*)hp = v;   // write-back, stays in shared L2
          else __hip_atomic_store(hp, v, __ATOMIC_RELAXED, __HIP_MEMORY_SCOPE_AGENT);
        }
        if (t == lenr[r] - 1)
          hfin[(size_t)bmr[r]*1024 + sp*512 + unit] = hF[r];
      }
    }
  }
  #undef HL
}

// ---------------- outk: out = sigmoid(hfin @ W_o^T + b_o) ----------------
__global__ void outk(const float* __restrict__ hfin, const float* __restrict__ W_o,
                     const float* __restrict__ b_o, float* __restrict__ out){
  __shared__ float hl[1024];
  __shared__ float red[16][17];
  const int b = blockIdx.x, tid = threadIdx.x;
  #pragma unroll
  for (int i = 0; i < 4; ++i) hl[tid + i*256] = hfin[(size_t)b*1024 + tid + i*256];
  __syncthreads();
  const int o = tid >> 4, j0 = tid & 15;
  float s = 0.f;
  if (o < 14){
    for (int j = j0; j < 1024; j += 16) s += hl[j]*W_o[(size_t)o*1024 + j];
  }
  red[o][j0] = s;
  __syncthreads();
  if (tid < 14){
    float tot = b_o[tid];
    #pragma unroll
    for (int i = 0; i < 16; ++i) tot += red[tid][i];
    out[b*14 + tid] = 1.0f/(1.0f + __expf(-tot));
  }
}

extern "C" void kernel_launch(void* const* d_in, const int* in_sizes, int n_in,
                              void* d_out, int out_size, void* d_ws, size_t ws_size,
                              hipStream_t stream){
  const float* x     = (const float*)d_in[0];
  const int*   lens  = (const int*)  d_in[1];
  const float* h0    = (const float*)d_in[2];
  const float* c0    = (const float*)d_in[3];
  const float* W_is0 = (const float*)d_in[4];
  const float* b_is0 = (const float*)d_in[5];
  const float* W_is1 = (const float*)d_in[6];
  const float* b_is1 = (const float*)d_in[7];
  const float* W_ih  = (const float*)d_in[8];
  const float* W_hh  = (const float*)d_in[9];
  const float* b_ih  = (const float*)d_in[10];
  const float* b_hh  = (const float*)d_in[11];
  const float* W_o   = (const float*)d_in[12];
  const float* b_o   = (const float*)d_in[13];
  float* out = (float*)d_out;

  char* ws = (char*)d_ws;   // needs ~74 MB
  uint16_t* G      = (uint16_t*)(ws + OFF_G);
  uint16_t* temb   = (uint16_t*)(ws + OFF_TEMB);
  uint16_t* h_hist = (uint16_t*)(ws + OFF_HH);
  uint16_t* whh_b  = (uint16_t*)(ws + OFF_WHH);
  uint16_t* wmid_b = (uint16_t*)(ws + OFF_WMID);
  float* wc0  = (float*)(ws + OFF_WC0);
  float* wc1  = (float*)(ws + OFF_WC1);
  float* bc   = (float*)(ws + OFF_BC);
  float* hfin = (float*)(ws + OFF_HFIN);
  uint32_t* gflag = (uint32_t*)(ws + OFF_GFLAG);
  uint32_t* xcdtab = (uint32_t*)(ws + OFF_XCDT);

  hipLaunchKernelGGL(prepAll, dim3(12416), dim3(256), 0, stream,
                     x, W_ih, W_hh, W_is0, b_is0, W_is1, b_is1, b_ih, b_hh, h0,
                     whh_b, wmid_b, wc0, wc1, bc, temb, h_hist, gflag, xcdtab);
  hipLaunchKernelGGL(fusedk, dim3(1152), dim3(256), 0, stream,
                     x, c0, lens, whh_b, temb, wmid_b, wc0, wc1, bc,
                     G, h_hist, gflag, xcdtab, hfin);
  hipLaunchKernelGGL(outk, dim3(64), dim3(256), 0, stream, hfin, W_o, b_o, out);
}

// Round 6
// 558.044 us; speedup vs baseline: 1.5672x; 1.5672x over previous
//
#include <hip/hip_runtime.h>
#include <hip/hip_bf16.h>
#include <stdint.h>

// Problem: B=64, T=128, F=16, H=512, S=2.  All inputs fp32, lengths int32, out fp32 [64][14].
//
// History: R2 1338us -> R3 relaxed poll 831 -> R5 poll-on-data 656 -> R6 coalesced poll 612
// -> R9 dense transactions (lstmk 400, MALL-RT floor) -> R11 gemmB m97-staging, total 590
// -> R12 fused gemm-under-recurrence 570 -> R13 gemm LDS swizzle (conflicts -70%, time
//    NEUTRAL -> gemm off critical path; 567us, best measured).
// Failed/abandoned: R4 release-flags, R7 poll backoff, R8 64x512, R10/R14/R15/R16 XCD-local
//    fast path (R14 write-through regressed 875; R15/R16 write-back hung twice -> same-XCC_ID
//    does not provably imply same-physical-L2 visibility for write-back stores; line is dead).
//
// R17 = R13 + busy-poll (no s_sleep) in the hot h-poll:
//   the recurrence is latency-bound (HBM 7.5%, MfmaUtil 6.2%); per-step cost = producer
//   store -> MALL visibility -> poll detect. s_sleep(1) between poll iterations adds
//   detection quantization (~64cy + wake, max-of-4-waves via the barrier). Continuous
//   re-issue costs only ~100GB/s extra MALL reads (negligible) and cannot hang.
//   R7 showed MORE waiting hurts; this is the opposite direction.
//
// Reshape quirk (faithful to torch): segment s', step t' uses source timestep n_t=(s'*128+t')>>1
// and embedding branch n_s=(s'*128+t')&1.

typedef __attribute__((ext_vector_type(8))) short bf16x8_t;
typedef __attribute__((ext_vector_type(4))) float f32x4_t;

#define SENT 0xAAAAAAAAu

// ---------------- workspace layout (bytes) ----------------
#define OFF_G      0u                      // bf16 [8192][2048] time-major rows  33,554,432
#define OFF_TEMB   33554432u               // bf16 [8192][1024]   16,777,216
#define OFF_HH     50331648u               // bf16 [129][8rr][16cg][16row][32u] 16,908,288
#define OFF_WHH    67239936u               // bf16 [2048][512]     2,097,152
#define OFF_WMID   69337088u               // bf16 [2048][1024]    4,194,304
#define OFF_WC0    73531392u               // f32  [2048][8]          65,536
#define OFF_WC1    73596928u               // f32  [2048][8] (6 used) 65,536
#define OFF_BC     73662464u               // f32  [2][2048]          16,384
#define OFF_HFIN   73678848u               // f32  [64][1024]        262,144
#define OFF_GFLAG  73940992u               // u32  [64][16]             4,096
// total ~74 MB

__device__ __forceinline__ float bf2f(uint16_t u){
  union { uint32_t i; float f; } v; v.i = ((uint32_t)u) << 16; return v.f;
}
__device__ __forceinline__ uint16_t f2b(float f){
  union { float f; uint32_t i; } v; v.f = f;
  uint32_t r = v.i + 0x7fffu + ((v.i >> 16) & 1u);  // RNE
  return (uint16_t)(r >> 16);
}
__device__ __forceinline__ float sigm(float x){ return 1.0f/(1.0f + __expf(-x)); }
__device__ __forceinline__ float tanh_(float x){
  float xc = fminf(fmaxf(x, -15.f), 15.f);
  float t = __expf(2.f*xc);
  return (t - 1.f)/(t + 1.f);
}
__device__ __forceinline__ void gl_lds16(const void* g, void* l){
  __builtin_amdgcn_global_load_lds(
      (const __attribute__((address_space(1))) void*)g,
      (__attribute__((address_space(3))) void*)l, 16, 0, 0);
}

// ---------------- prepAll: prep1(2048) | tembk(8192) | lvl0+gflag(128) | sentinel(2048) ------
__global__ void prepAll(const float* __restrict__ x,
                        const float* __restrict__ W_ih, const float* __restrict__ W_hh,
                        const float* __restrict__ W_is0, const float* __restrict__ b_is0,
                        const float* __restrict__ W_is1, const float* __restrict__ b_is1,
                        const float* __restrict__ b_ih, const float* __restrict__ b_hh,
                        const float* __restrict__ h0,
                        uint16_t* __restrict__ whh_b, uint16_t* __restrict__ wmid_b,
                        float* __restrict__ wc0, float* __restrict__ wc1,
                        float* __restrict__ bc,
                        uint16_t* __restrict__ temb, uint16_t* __restrict__ h_hist,
                        uint32_t* __restrict__ gflag){
  const int bid = blockIdx.x, tid = threadIdx.x;
  if (bid < 2048){
    // ---- prep1 role: weight folding + bf16 casts ----
    const int n = bid;
    __shared__ float wrow[512];
    __shared__ float red[16][17];
    wrow[tid]       = W_ih[(size_t)n*1536 + tid];
    wrow[tid + 256] = W_ih[(size_t)n*1536 + 256 + tid];
    for (int j = tid; j < 1024; j += 256)
      wmid_b[(size_t)n*1024 + j] = f2b(W_ih[(size_t)n*1536 + 512 + j]);
    for (int k = tid; k < 512; k += 256)
      whh_b[(size_t)n*512 + k] = f2b(W_hh[(size_t)n*512 + k]);
    __syncthreads();
    {
      const int d = tid >> 4, jp = tid & 15;
      float s = 0.f;
      const int kk0 = jp*32;
      if (d < 8){
        for (int k = kk0; k < kk0 + 32; ++k) s += wrow[k]*W_is0[k*8 + d];
      } else if (d < 14){
        int c = d - 8;
        for (int k = kk0; k < kk0 + 32; ++k) s += wrow[k]*W_is1[k*6 + c];
      } else if (d == 14){
        for (int k = kk0; k < kk0 + 32; ++k) s += wrow[k]*b_is0[k];
      } else {
        for (int k = kk0; k < kk0 + 32; ++k) s += wrow[k]*b_is1[k];
      }
      red[d][jp] = s;
    }
    __syncthreads();
    if (tid < 16){
      float tot = 0.f;
      #pragma unroll
      for (int i = 0; i < 16; ++i) tot += red[tid][i];
      if (tid < 8)        wc0[n*8 + tid] = tot;
      else if (tid < 14)  wc1[n*8 + (tid - 8)] = tot;
      else if (tid == 14) bc[n]        = b_ih[n] + b_hh[n] + tot;
      else                bc[2048 + n] = b_ih[n] + b_hh[n] + tot;
    } else if (tid == 16){
      wc1[n*8 + 6] = 0.f; wc1[n*8 + 7] = 0.f;
    }
  } else if (bid < 10240){
    // ---- tembk role ----
    const int rid = bid - 2048;       // (b*128 + t)
    const int k = tid;
    float x0 = x[(size_t)rid*16 + 0], x1 = x[(size_t)rid*16 + 1];
    float f = __expf((float)k * (-9.210340371976184f/256.f));
    float a0 = x0*f, a1 = x1*f;
    size_t base = (size_t)rid*1024;
    temb[base + k]        = f2b(__cosf(a0));
    temb[base + 256 + k]  = f2b(__sinf(a0));
    temb[base + 512 + k]  = f2b(__cosf(a1));
    temb[base + 768 + k]  = f2b(__sinf(a1));
  } else if (bid < 10368){
    // ---- level-0 h + gflag zero ----
    int i = (bid - 10240)*256 + tid;   // 0..32767
    uint32_t* hh = (uint32_t*)h_hist;
    int e    = i*2;
    int rrcg = e >> 9;
    int rr   = rrcg >> 4, cg = rrcg & 15;
    int rm   = e & 511;
    int row  = rm >> 5, u = rm & 31;
    int b    = (rr*16 + row) & 63;
    int unit = cg*32 + u;
    uint32_t lo = f2b(h0[(size_t)b*512 + unit]);
    uint32_t hi = f2b(h0[(size_t)b*512 + unit + 1]);
    uint32_t wd = lo | (hi << 16);
    if (wd == SENT) wd ^= 1u;
    hh[i] = wd;
    if (i < 1024) gflag[i] = 0u;
  } else {
    // ---- sentinel fill role: words [32768, 4227072), 8 per thread via 2x uint4 ----
    uint32_t* hh = (uint32_t*)h_hist;
    size_t w0 = 32768u + ((size_t)(bid - 10368)*256 + tid)*8;
    uint4 s4 = make_uint4(SENT, SENT, SENT, SENT);
    *(uint4*)&hh[w0]     = s4;
    *(uint4*)&hh[w0 + 4] = s4;
  }
}

// ---------------- fused: lstm role (bid 0..127) + gemm role (bid 128..1151) ----------------
// lstm: 8 row-groups x 16 col-groups, blockIdx = g*8 + rr (R9-exact protocol).
// h_hist level layout: [rr][cg16][16row][32u], 1KB/region. G time-major: row' = ntm*64 + b.
__launch_bounds__(256)
__global__ void fusedk(const float* __restrict__ x, const float* __restrict__ c0,
                       const int* __restrict__ lengths,
                       const uint16_t* __restrict__ whh_b, const uint16_t* __restrict__ temb,
                       const uint16_t* __restrict__ wmid,
                       const float* __restrict__ wc0, const float* __restrict__ wc1,
                       const float* __restrict__ bc,
                       uint16_t* __restrict__ G, uint16_t* __restrict__ h_hist,
                       uint32_t* __restrict__ gflag, float* __restrict__ hfin){
  __shared__ __align__(16) uint16_t smem_u[17664];   // lstm: h_l[2][16][552]; gemm: tiles+bounce
  const int tid = threadIdx.x;
  const int bid = blockIdx.x;
  const int w = tid >> 6, lane = tid & 63;
  const int q = lane >> 4, ln = lane & 15;

  if (bid >= 128){
    // ================= gemm role =================
    const int gb = bid - 128;
    const int idx = gb >> 4;
    const int mt = (idx & 1) ? (idx >> 1) : (32 + (idx >> 1));  // seg1 tiles first
    const int n0 = (gb & 15)*128;
    uint16_t* Al = smem_u;
    uint16_t* Bl = smem_u + 8192;
    const int wm = w >> 1, wn = w & 1;
    // T2 swizzle: LDS dest stays LINEAR (global_load_lds writes base+lane*16); the
    // per-lane GLOBAL source fetches chunk (l&7)^(l>>3) of its row (row0&7==0 always),
    // so LDS row r holds chunk cc at 16B-slot cc^(r&7). Reads XOR the same involution.
    const int srow_l = lane >> 3;
    const int scol = (((lane & 7) ^ srow_l)) * 8;   // swizzled source col (elements)

    f32x4_t acc[4][4];
    #pragma unroll
    for (int a = 0; a < 4; ++a)
      #pragma unroll
      for (int b2 = 0; b2 < 4; ++b2) acc[a][b2] = (f32x4_t){0.f,0.f,0.f,0.f};

    for (int kb = 0; kb < 16; ++kb){
      #pragma unroll
      for (int i = 0; i < 4; ++i){
        int row0 = w*32 + i*8;
        int lrow = row0 + srow_l;
        int bA = lrow & 63, ntmA = mt*2 + (lrow >> 6);
        gl_lds16(temb + (size_t)(bA*128 + ntmA)*1024 + kb*64 + scol, &Al[row0*64]);
        gl_lds16(wmid + (size_t)(n0 + lrow)*1024 + kb*64 + scol, &Bl[row0*64]);
      }
      __syncthreads();
      #pragma unroll
      for (int kc = 0; kc < 2; ++kc){
        const int sl = ((((kc << 2) | q) ^ (ln & 7)) << 3);  // swizzled 16B slot (elements)
        bf16x8_t af[4], bf[4];
        #pragma unroll
        for (int mt_i = 0; mt_i < 4; ++mt_i)
          af[mt_i] = *(const bf16x8_t*)&Al[(wm*64 + mt_i*16 + ln)*64 + sl];
        #pragma unroll
        for (int nt = 0; nt < 4; ++nt)
          bf[nt] = *(const bf16x8_t*)&Bl[(wn*64 + nt*16 + ln)*64 + sl];
        #pragma unroll
        for (int mt_i = 0; mt_i < 4; ++mt_i)
          #pragma unroll
          for (int nt = 0; nt < 4; ++nt)
            acc[mt_i][nt] = __builtin_amdgcn_mfma_f32_16x16x32_bf16(af[mt_i], bf[nt], acc[mt_i][nt], 0, 0, 0);
      }
      __syncthreads();
    }
    // C bounce (C/D: col=lane&15, row=quad*4+reg — m89-verified). Stride 132 (pad) to
    // break the old 8-way bank conflict on the b16 scatter (128*132 = 16896 <= 17664).
    #pragma unroll
    for (int mt_i = 0; mt_i < 4; ++mt_i)
      #pragma unroll
      for (int nt = 0; nt < 4; ++nt)
        #pragma unroll
        for (int r = 0; r < 4; ++r){
          int Mr = wm*64 + mt_i*16 + q*4 + r;
          int Nc = wn*64 + nt*16 + ln;
          smem_u[Mr*132 + Nc] = f2b(acc[mt_i][nt][r]);
        }
    __syncthreads();
    // epilogue: agent-scope (MALL write-through) stores, 128B/thread contiguous
    {
      const int erow = tid >> 1, eh = tid & 1;
      const unsigned long long* lsrc = (const unsigned long long*)&smem_u[erow*132 + eh*64];
      unsigned long long* gdst = (unsigned long long*)
          (G + (size_t)(mt*128 + erow)*2048 + n0 + eh*64);
      #pragma unroll
      for (int i2 = 0; i2 < 16; ++i2)
        __hip_atomic_store(&gdst[i2], lsrc[i2], __ATOMIC_RELAXED, __HIP_MEMORY_SCOPE_AGENT);
    }
    __syncthreads();   // each wave drains vmcnt(0) before barrier -> all stores in MALL
    if (tid == 0)
      __hip_atomic_store(&gflag[mt*16 + (gb & 15)], 1u,
                         __ATOMIC_RELEASE, __HIP_MEMORY_SCOPE_AGENT);
    return;
  }

  // ================= lstm role (R9-exact + time-major G + prefetched gflag gating) =========
  #define HL(b,r,c) smem_u[(((b)*16 + (r))*552) + (c)]
  const int rr = bid & 7;
  const int g  = bid >> 3;
  const int k0 = g*32;
  const int sp = rr >> 2;
  const int u8 = ln & 7, gh = ln >> 3;
  const int unit = k0 + w*8 + u8;
  const int gl0 = gh*512 + unit;
  const int gl1 = (2 + gh)*512 + unit;
  const int LVL = 65536;

  bf16x8_t barr0[16], barr1[16];
  #pragma unroll
  for (int kc = 0; kc < 16; ++kc){
    barr0[kc] = *(const bf16x8_t*)(whh_b + (size_t)gl0*512 + kc*32 + q*8);
    barr1[kc] = *(const bf16x8_t*)(whh_b + (size_t)gl1*512 + kc*32 + q*8);
  }
  bf16x8_t e0f[2], e1f[2];
  #pragma unroll
  for (int nsI = 0; nsI < 2; ++nsI){
    bf16x8_t v0 = {0,0,0,0,0,0,0,0}, v1 = {0,0,0,0,0,0,0,0};
    if (q == 0){
      const float* wcs = nsI ? wc1 : wc0;
      #pragma unroll
      for (int jj = 0; jj < 8; ++jj){
        ((uint16_t*)&v0)[jj] = f2b(wcs[gl0*8 + jj]);
        ((uint16_t*)&v1)[jj] = f2b(wcs[gl1*8 + jj]);
      }
    }
    e0f[nsI] = v0; e1f[nsI] = v1;
  }
  float bc0v[2] = { bc[gl0], bc[2048 + gl0] };
  float bc1v[2] = { bc[gl1], bc[2048 + gl1] };

  int   bmr[4], lenr[4];
  float cst[4];
  #pragma unroll
  for (int r = 0; r < 4; ++r){
    int row = rr*16 + q*4 + r;
    bmr[r]  = row & 63;
    lenr[r] = lengths[bmr[r]];
    cst[r]  = c0[(size_t)bmr[r]*512 + unit];
  }

  const int prow = lane >> 2;
  const int pcol = (lane & 3)*8;
  const int xm = tid >> 3, xc = tid & 7;
  const int xb = (rr*16 + xm) & 63;
  const size_t stb = ((size_t)rr*8192 + g*512);

  for (int idx2 = tid; idx2 < 2*16*32; idx2 += 256)
    HL(idx2 >> 9, (idx2 >> 5) & 15, 520 + (idx2 & 31)) = 0;

  // gflag prefetch: fl[] holds flags for the NEXT boundary's m-tile, loaded 4 steps
  // early (latency hidden under the h-poll). Spin fallback keeps correctness.
  uint32_t fl[4];
  {
    const uint32_t* gf0 = gflag + (sp*32)*16 + (g >> 2);
    #pragma unroll
    for (int j = 0; j < 4; ++j)
      fl[j] = __hip_atomic_load(&gf0[j*4], __ATOMIC_RELAXED, __HIP_MEMORY_SCOPE_AGENT);
  }

  for (int t = 0; t < 128; ++t){
    const int qidx = sp*128 + t;
    const int ntm = qidx >> 1;
    const int ns  = qidx & 1;
    const int buf = t & 1;

    // --- gate on G m-tile readiness (prefetched; spin only if stale-false) ---
    if ((t & 3) == 0){
      const int mt = qidx >> 2;
      bool ok = (fl[0] != 0u) & (fl[1] != 0u) & (fl[2] != 0u) & (fl[3] != 0u);
      if (!ok){
        const uint32_t* gf = gflag + mt*16 + (g >> 2);
        while (true){
          ok = true;
          #pragma unroll
          for (int j = 0; j < 4; ++j){
            uint32_t v = __hip_atomic_load(&gf[j*4], __ATOMIC_RELAXED, __HIP_MEMORY_SCOPE_AGENT);
            ok &= (v != 0u);
          }
          if (ok) break;
          __builtin_amdgcn_s_sleep(1);
        }
      }
      if (t < 124){
        const uint32_t* gfn = gflag + (mt + 1)*16 + (g >> 2);
        #pragma unroll
        for (int j = 0; j < 4; ++j)
          fl[j] = __hip_atomic_load(&gfn[j*4], __ATOMIC_RELAXED, __HIP_MEMORY_SCOPE_AGENT);
      }
    }

    // --- early independent loads: G slice (time-major rows, cached) + xf source ---
    uint16_t g0r[4], g1r[4];
    #pragma unroll
    for (int r = 0; r < 4; ++r){
      size_t grow = (size_t)(ntm*64 + bmr[r])*2048;
      g0r[r] = G[grow + gl0];
      g1r[r] = G[grow + gl1];
    }
    float xv = 0.f;
    if (tid < 128){
      if (ns == 0)      xv = x[(size_t)(xb*128 + ntm)*16 + 2 + xc];
      else if (xc < 6)  xv = x[(size_t)(xb*128 + ntm)*16 + 10 + xc];
    }

    // --- hot poll-on-data, lane-dense (R9); R17: busy-poll, no sleep ---
    {
      const unsigned long long* lvl = (const unsigned long long*)h_hist
                                      + (((size_t)t*LVL + (size_t)rr*8192) >> 2);
      unsigned long long hv[4][2];
      while (true){
        bool ok = true;
        #pragma unroll
        for (int i = 0; i < 4; ++i){
          const unsigned long long* p = lvl + ((size_t)(w*4 + i)*128 + prow*8 + (pcol >> 2));
          hv[i][0] = __hip_atomic_load(&p[0], __ATOMIC_RELAXED, __HIP_MEMORY_SCOPE_AGENT);
          hv[i][1] = __hip_atomic_load(&p[1], __ATOMIC_RELAXED, __HIP_MEMORY_SCOPE_AGENT);
          ok &= ((uint32_t)hv[i][0] != SENT) & ((uint32_t)(hv[i][0] >> 32) != SENT)
              & ((uint32_t)hv[i][1] != SENT) & ((uint32_t)(hv[i][1] >> 32) != SENT);
        }
        if (__all(ok)) break;
      }
      #pragma unroll
      for (int i = 0; i < 4; ++i){
        int reg = w*4 + i;
        *(unsigned long long*)&HL(buf, prow, reg*32 + pcol)     = hv[i][0];
        *(unsigned long long*)&HL(buf, prow, reg*32 + pcol + 4) = hv[i][1];
      }
    }
    if (tid < 128) HL(buf, xm, 512 + xc) = f2b(xv);
    __syncthreads();

    // --- gates = G + bias + [h|xf] @ [Whh|Wc]^T ---
    f32x4_t acc0, acc1;
    {
      float b0 = ns ? bc0v[1] : bc0v[0];
      float b1 = ns ? bc1v[1] : bc1v[0];
      #pragma unroll
      for (int r = 0; r < 4; ++r){ acc0[r] = bf2f(g0r[r]) + b0; acc1[r] = bf2f(g1r[r]) + b1; }
    }
    #pragma unroll
    for (int kc = 0; kc < 16; ++kc){
      bf16x8_t a = *(const bf16x8_t*)&HL(buf, ln, kc*32 + q*8);
      acc0 = __builtin_amdgcn_mfma_f32_16x16x32_bf16(a, barr0[kc], acc0, 0, 0, 0);
      acc1 = __builtin_amdgcn_mfma_f32_16x16x32_bf16(a, barr1[kc], acc1, 0, 0, 0);
    }
    {
      bf16x8_t a = *(const bf16x8_t*)&HL(buf, ln, 512 + q*8);
      acc0 = __builtin_amdgcn_mfma_f32_16x16x32_bf16(a, ns ? e0f[1] : e0f[0], acc0, 0, 0, 0);
      acc1 = __builtin_amdgcn_mfma_f32_16x16x32_bf16(a, ns ? e1f[1] : e1f[0], acc1, 0, 0, 0);
    }

    float pf[4], po[4];
    #pragma unroll
    for (int r = 0; r < 4; ++r){
      pf[r] = __shfl_xor(acc0[r], 8);
      po[r] = __shfl_xor(acc1[r], 8);
    }
    if (ln < 8){
      uint32_t hb[4]; float hF[4];
      #pragma unroll
      for (int r = 0; r < 4; ++r){
        float ig = acc0[r], fg = pf[r], gg = acc1[r], og = po[r];
        cst[r] = sigm(fg)*cst[r] + sigm(ig)*tanh_(gg);
        float h = sigm(og)*tanh_(cst[r]);
        hF[r] = h; hb[r] = (uint32_t)f2b(h);
      }
      #pragma unroll
      for (int r = 0; r < 4; ++r){
        uint32_t ph = (uint32_t)__shfl_xor((int)hb[r], 1);
        uint32_t packed = hb[r] | (ph << 16);
        if (packed == SENT) packed ^= 1u;
        uint32_t hi = (uint32_t)__shfl_xor((int)packed, 2);
        if ((ln & 3) == 0){
          unsigned long long v = (unsigned long long)packed | ((unsigned long long)hi << 32);
          unsigned long long* hp = (unsigned long long*)h_hist
              + (((size_t)(t+1)*LVL + stb + (size_t)(q*4 + r)*32 + w*8 + u8) >> 2);
          __hip_atomic_store(hp, v, __ATOMIC_RELAXED, __HIP_MEMORY_SCOPE_AGENT);
        }
        if (t == lenr[r] - 1)
          hfin[(size_t)bmr[r]*1024 + sp*512 + unit] = hF[r];
      }
    }
  }
  #undef HL
}

// ---------------- outk: out = sigmoid(hfin @ W_o^T + b_o) ----------------
__global__ void outk(const float* __restrict__ hfin, const float* __restrict__ W_o,
                     const float* __restrict__ b_o, float* __restrict__ out){
  __shared__ float hl[1024];
  __shared__ float red[16][17];
  const int b = blockIdx.x, tid = threadIdx.x;
  #pragma unroll
  for (int i = 0; i < 4; ++i) hl[tid + i*256] = hfin[(size_t)b*1024 + tid + i*256];
  __syncthreads();
  const int o = tid >> 4, j0 = tid & 15;
  float s = 0.f;
  if (o < 14){
    for (int j = j0; j < 1024; j += 16) s += hl[j]*W_o[(size_t)o*1024 + j];
  }
  red[o][j0] = s;
  __syncthreads();
  if (tid < 14){
    float tot = b_o[tid];
    #pragma unroll
    for (int i = 0; i < 16; ++i) tot += red[tid][i];
    out[b*14 + tid] = 1.0f/(1.0f + __expf(-tot));
  }
}

extern "C" void kernel_launch(void* const* d_in, const int* in_sizes, int n_in,
                              void* d_out, int out_size, void* d_ws, size_t ws_size,
                              hipStream_t stream){
  const float* x     = (const float*)d_in[0];
  const int*   lens  = (const int*)  d_in[1];
  const float* h0    = (const float*)d_in[2];
  const float* c0    = (const float*)d_in[3];
  const float* W_is0 = (const float*)d_in[4];
  const float* b_is0 = (const float*)d_in[5];
  const float* W_is1 = (const float*)d_in[6];
  const float* b_is1 = (const float*)d_in[7];
  const float* W_ih  = (const float*)d_in[8];
  const float* W_hh  = (const float*)d_in[9];
  const float* b_ih  = (const float*)d_in[10];
  const float* b_hh  = (const float*)d_in[11];
  const float* W_o   = (const float*)d_in[12];
  const float* b_o   = (const float*)d_in[13];
  float* out = (float*)d_out;

  char* ws = (char*)d_ws;   // needs ~74 MB
  uint16_t* G      = (uint16_t*)(ws + OFF_G);
  uint16_t* temb   = (uint16_t*)(ws + OFF_TEMB);
  uint16_t* h_hist = (uint16_t*)(ws + OFF_HH);
  uint16_t* whh_b  = (uint16_t*)(ws + OFF_WHH);
  uint16_t* wmid_b = (uint16_t*)(ws + OFF_WMID);
  float* wc0  = (float*)(ws + OFF_WC0);
  float* wc1  = (float*)(ws + OFF_WC1);
  float* bc   = (float*)(ws + OFF_BC);
  float* hfin = (float*)(ws + OFF_HFIN);
  uint32_t* gflag = (uint32_t*)(ws + OFF_GFLAG);

  hipLaunchKernelGGL(prepAll, dim3(12416), dim3(256), 0, stream,
                     x, W_ih, W_hh, W_is0, b_is0, W_is1, b_is1, b_ih, b_hh, h0,
                     whh_b, wmid_b, wc0, wc1, bc, temb, h_hist, gflag);
  hipLaunchKernelGGL(fusedk, dim3(1152), dim3(256), 0, stream,
                     x, c0, lens, whh_b, temb, wmid_b, wc0, wc1, bc,
                     G, h_hist, gflag, hfin);
  hipLaunchKernelGGL(outk, dim3(64), dim3(256), 0, stream, hfin, W_o, b_o, out);
}